// Round 2
// baseline (7445.309 us; speedup 1.0000x reference)
//
#include <hip/hip_runtime.h>
#include <math.h>

#define BB 256
#define NEL 90
#define NMAX 270
#define C1 448
#define C2 256
#define PIN 448
#define LATH 128
#define SGE 64
#define P1 512
#define EPSB 1e-5f

__device__ __forceinline__ float bf2f(unsigned short u) {
  return __uint_as_float(((unsigned)u) << 16);
}
__device__ __forceinline__ unsigned short f2bf(float f) {
  unsigned x = __float_as_uint(f);
  unsigned r = (x + 0x7fffu + ((x >> 16) & 1u)) >> 16;
  return (unsigned short)r;
}

// ---------------- prep: cumsum -> z, n_atoms, sg_x, lat MLP ----------------
__global__ __launch_bounds__(256) void k_prep(
    const int* __restrict__ comp, const int* __restrict__ sg, const float* __restrict__ lat,
    const float* __restrict__ sg_emb,
    const float* __restrict__ W1, const float* __restrict__ b1,
    const float* __restrict__ g1, const float* __restrict__ be1,
    const float* __restrict__ m1, const float* __restrict__ v1,
    const float* __restrict__ W2, const float* __restrict__ b2,
    const float* __restrict__ g2, const float* __restrict__ be2,
    const float* __restrict__ m2, const float* __restrict__ v2,
    float* __restrict__ sgx, float* __restrict__ latx,
    int* __restrict__ z, int* __restrict__ natoms) {
  int b = blockIdx.x;
  int tid = threadIdx.x;
  __shared__ int cum[NEL];
  __shared__ float hbuf[LATH];
  __shared__ float latl[6];
  if (tid == 0) {
    int s = 0;
    for (int e = 0; e < NEL; ++e) { s += comp[b * NEL + e]; cum[e] = s; }
    natoms[b] = s;
  }
  if (tid < 6) latl[tid] = lat[b * 6 + tid];
  __syncthreads();
  int n = cum[NEL - 1];
  for (int t = tid; t < NMAX; t += blockDim.x) {
    int zz = -1;
    if (t < n) {
      for (int e = 0; e < NEL; ++e) { if (cum[e] > t) { zz = e; break; } }
    }
    z[b * NMAX + t] = zz;
  }
  if (tid < SGE) {
    int si = sg[b];
    sgx[b * SGE + tid] = sg_emb[si * SGE + tid];
  }
  if (tid < LATH) {
    float acc = b1[tid];
    for (int k = 0; k < 6; ++k) acc += latl[k] * W1[k * LATH + tid];
    acc = (acc - m1[tid]) * g1[tid] * rsqrtf(v1[tid] + EPSB) + be1[tid];
    hbuf[tid] = acc;
  }
  __syncthreads();
  if (tid < LATH) {
    float acc = b2[tid];
    for (int k = 0; k < LATH; ++k) acc += hbuf[k] * W2[k * LATH + tid];
    acc = (acc - m2[tid]) * g2[tid] * rsqrtf(v2[tid] + EPSB) + be2[tid];
    latx[b * LATH + tid] = acc;
  }
}

// ---------------- exclusive scan of natoms -> off ----------------
__global__ __launch_bounds__(256) void k_scan(const int* __restrict__ natoms,
                                              int* __restrict__ off) {
  __shared__ int sh[BB];
  int tid = threadIdx.x;
  int v0 = natoms[tid];
  sh[tid] = v0;
  for (int d = 1; d < BB; d <<= 1) {
    __syncthreads();
    int v = (tid >= d) ? sh[tid - d] : 0;
    __syncthreads();
    sh[tid] += v;
  }
  __syncthreads();
  off[tid] = sh[tid] - v0;
}

// ---------------- per-element-type phys rows: [90,256] ----------------
__global__ __launch_bounds__(256) void k_physpe(
    const int* __restrict__ period_idx, const int* __restrict__ group_idx,
    const float* __restrict__ z_emb, const float* __restrict__ period_t,
    const float* __restrict__ group_t, const float* __restrict__ props,
    const float* __restrict__ Wp, const float* __restrict__ bp,
    const float* __restrict__ Wphys, const float* __restrict__ bphys,
    float* __restrict__ physpe) {
  int e = blockIdx.x;
  int tid = threadIdx.x;
  __shared__ float ph[128];
  if (tid < 32) ph[tid] = z_emb[e * 32 + tid];
  else if (tid < 64) ph[tid] = period_t[period_idx[e] * 32 + tid - 32];
  else if (tid < 96) ph[tid] = group_t[group_idx[e] * 32 + tid - 64];
  else if (tid < 128) {
    int j = tid - 96;
    float acc = bp[j];
    for (int k = 0; k < 20; ++k) acc += props[e * 20 + k] * Wp[k * 32 + j];
    ph[tid] = acc;
  }
  __syncthreads();
  float acc = bphys[tid];
  for (int k = 0; k < 128; ++k) acc += ph[k] * Wphys[k * 256 + tid];
  physpe[e * 256 + tid] = acc;
}

// ---------------- packed node features x0 [total,448] bf16 ----------------
__global__ __launch_bounds__(256) void k_nodep(
    const int* __restrict__ z, const int* __restrict__ off, const int* __restrict__ natoms,
    const float* __restrict__ physpe, const float* __restrict__ latx,
    const float* __restrict__ sgx, unsigned short* __restrict__ x0) {
  int b = blockIdx.x;
  int n = natoms[b], ob = off[b];
  int tid = threadIdx.x;
  for (int e = tid; e < n * PIN; e += 256) {
    int t = e / PIN, c = e % PIN;
    int zt = z[b * NMAX + t];
    float v = (c < 256) ? physpe[zt * 256 + c]
            : (c < 384) ? latx[b * LATH + (c - 256)]
                        : sgx[b * SGE + (c - 384)];
    x0[(size_t)(ob + t) * PIN + c] = f2bf(v);
  }
}

// ---------------- fold a_s/a_d through W: wsv/wdv [K][3] ----------------
__global__ __launch_bounds__(64) void k_fold(
    const float* __restrict__ W, const float* __restrict__ a_s, const float* __restrict__ a_d,
    int NC3, int C, float* __restrict__ wsv, float* __restrict__ wdv) {
  int k = blockIdx.x;
  int tid = threadIdx.x;
  for (int h = 0; h < 3; ++h) {
    float ss = 0.f, sd = 0.f;
    for (int c = tid; c < C; c += 64) {
      float wv = W[(size_t)k * NC3 + h * C + c];
      ss += wv * a_s[h * C + c];
      sd += wv * a_d[h * C + c];
    }
    for (int o = 32; o > 0; o >>= 1) { ss += __shfl_down(ss, o); sd += __shfl_down(sd, o); }
    if (tid == 0) { wsv[k * 3 + h] = ss; wdv[k * 3 + h] = sd; }
  }
}

// ---------------- asrc/adst for packed rows ----------------
__global__ __launch_bounds__(64) void k_av2(
    const unsigned short* __restrict__ x, const float* __restrict__ wsv,
    const float* __restrict__ wdv, const int* __restrict__ off,
    const int* __restrict__ natoms, float* __restrict__ asrc,
    float* __restrict__ adst, int K) {
  int row = blockIdx.x;
  int total = off[BB - 1] + natoms[BB - 1];
  if (row >= total) return;
  int tid = threadIdx.x;
  float s0 = 0.f, s1 = 0.f, s2 = 0.f, d0 = 0.f, d1 = 0.f, d2 = 0.f;
  for (int k = tid; k < K; k += 64) {
    float xv = bf2f(x[(size_t)row * K + k]);
    s0 += xv * wsv[k * 3 + 0]; s1 += xv * wsv[k * 3 + 1]; s2 += xv * wsv[k * 3 + 2];
    d0 += xv * wdv[k * 3 + 0]; d1 += xv * wdv[k * 3 + 1]; d2 += xv * wdv[k * 3 + 2];
  }
  for (int o = 32; o > 0; o >>= 1) {
    s0 += __shfl_down(s0, o); s1 += __shfl_down(s1, o); s2 += __shfl_down(s2, o);
    d0 += __shfl_down(d0, o); d1 += __shfl_down(d1, o); d2 += __shfl_down(d2, o);
  }
  if (tid == 0) {
    asrc[row * 3 + 0] = s0; asrc[row * 3 + 1] = s1; asrc[row * 3 + 2] = s2;
    adst[row * 3 + 0] = d0; adst[row * 3 + 1] = d1; adst[row * 3 + 2] = d2;
  }
}

// ---------------- per-row softmax stats (packed, j<n) ----------------
__global__ __launch_bounds__(256) void k_stats2(
    const float* __restrict__ asrc, const float* __restrict__ adst,
    const int* __restrict__ off, const int* __restrict__ natoms,
    float* __restrict__ rowm, float* __restrict__ rowsum) {
  int b = blockIdx.x;
  int n = natoms[b], ob = off[b];
  __shared__ float as_l[NMAX * 3];
  int tid = threadIdx.x;
  for (int e = tid; e < n * 3; e += 256) as_l[e] = asrc[ob * 3 + e];
  __syncthreads();
  for (int i = tid; i < n; i += 256) {
    for (int h = 0; h < 3; ++h) {
      float adv = adst[(ob + i) * 3 + h];
      float m = -1e30f;
      for (int j = 0; j < n; ++j) {
        float sc = as_l[j * 3 + h] + adv;
        sc = sc >= 0.f ? sc : 0.2f * sc;
        m = fmaxf(m, sc);
      }
      float s = 0.f;
      for (int j = 0; j < n; ++j) {
        float sc = as_l[j * 3 + h] + adv;
        sc = sc >= 0.f ? sc : 0.2f * sc;
        s += __expf(sc - m);
      }
      rowm[(ob + i) * 3 + h] = m;
      rowsum[(ob + i) * 3 + h] = s;
    }
  }
}

// ---------------- fused GAT layer: out = mean_h(alpha_h @ (x@W_h)) + bias ----
// grid (C/32, BB), 256 threads. LDS: xs/alpha union fp32[270][34],
// t bf16[270][36], wsm fp32[32][32], per-head vectors. Static LDS 63.1 KB.
__global__ __launch_bounds__(256) void k_fused(
    const unsigned short* __restrict__ xin, const float* __restrict__ W,
    const float* __restrict__ asrc, const float* __restrict__ adst,
    const float* __restrict__ rowm, const float* __restrict__ rowsum,
    const int* __restrict__ off, const int* __restrict__ natoms,
    const float* __restrict__ bias, unsigned short* __restrict__ xout,
    int K, int C, int NC3) {
  int b = blockIdx.y;
  int n = natoms[b];
  if (n == 0) return;
  int ob = off[b];
  int c0 = blockIdx.x * 32;
  int tid = threadIdx.x;
  int jy = tid & 31;        // row lane
  int cx = tid >> 5;        // 0..7 column group
  int cc = cx * 4;

  __shared__ float sm_xa[NMAX * 34];          // xs (phase1) / alpha (phase2)
  __shared__ unsigned short sm_t[NMAX * 36];  // t tile, bf16
  __shared__ float sm_w[32 * 32];
  __shared__ float sm_as[NMAX], sm_ad[NMAX], sm_m[NMAX], sm_rs[NMAX];

  float acc[9][4] = {};

  for (int h = 0; h < 3; ++h) {
    __syncthreads();
    for (int i = tid; i < n; i += 256) {
      sm_as[i] = asrc[(ob + i) * 3 + h];
      sm_ad[i] = adst[(ob + i) * 3 + h];
      sm_m[i]  = rowm[(ob + i) * 3 + h];
      sm_rs[i] = 1.f / rowsum[(ob + i) * 3 + h];
    }
    // ---- phase 1: t[j, 0:32] = x[j,:] @ W[:, h*C + c0 : +32] ----
    float tac[9][4] = {};
    for (int k0 = 0; k0 < K; k0 += 32) {
      __syncthreads();
      for (int e4 = tid * 4; e4 < NMAX * 32; e4 += 1024) {
        int j = e4 >> 5, kk = e4 & 31;
        float v0 = 0.f, v1 = 0.f, v2 = 0.f, v3 = 0.f;
        if (j < n) {
          ushort4 u = *(const ushort4*)(xin + (size_t)(ob + j) * K + k0 + kk);
          v0 = bf2f(u.x); v1 = bf2f(u.y); v2 = bf2f(u.z); v3 = bf2f(u.w);
        }
        float* xr = sm_xa + j * 34 + kk;
        xr[0] = v0; xr[1] = v1; xr[2] = v2; xr[3] = v3;
      }
      {
        int e4 = tid * 4;
        int kk = e4 >> 5, c = e4 & 31;
        float4 wv = *(const float4*)(W + (size_t)(k0 + kk) * NC3 + h * C + c0 + c);
        *(float4*)(sm_w + kk * 32 + c) = wv;
      }
      __syncthreads();
      for (int kk = 0; kk < 32; ++kk) {
        float4 wq = *(const float4*)(sm_w + kk * 32 + cc);
        #pragma unroll
        for (int r = 0; r < 9; ++r) {
          int j = jy + 32 * r;
          if (j < n) {
            float xv = sm_xa[j * 34 + kk];
            tac[r][0] += xv * wq.x; tac[r][1] += xv * wq.y;
            tac[r][2] += xv * wq.z; tac[r][3] += xv * wq.w;
          }
        }
      }
    }
    __syncthreads();
    #pragma unroll
    for (int r = 0; r < 9; ++r) {
      int j = jy + 32 * r;
      if (j < n) {
        ushort4 u;
        u.x = f2bf(tac[r][0]); u.y = f2bf(tac[r][1]);
        u.z = f2bf(tac[r][2]); u.w = f2bf(tac[r][3]);
        *(ushort4*)(sm_t + j * 36 + cc) = u;
      }
    }
    // ---- phase 2: acc += alpha_h @ t ----
    for (int j0 = 0; j0 < n; j0 += 32) {
      int jm = min(32, n - j0);
      __syncthreads();
      #pragma unroll
      for (int r = 0; r < 9; ++r) {
        int i = jy + 32 * r;
        if (i < n) {
          float ad = sm_ad[i], mi = sm_m[i], rs = sm_rs[i];
          #pragma unroll
          for (int q = 0; q < 4; ++q) {
            int jj = cc + q;
            if (jj < jm) {
              float sc = sm_as[j0 + jj] + ad;
              sc = sc >= 0.f ? sc : 0.2f * sc;
              sm_xa[i * 34 + jj] = __expf(sc - mi) * rs;
            }
          }
        }
      }
      __syncthreads();
      for (int jj = 0; jj < jm; ++jj) {
        ushort4 u = *(const ushort4*)(sm_t + (j0 + jj) * 36 + cc);
        float t0 = bf2f(u.x), t1 = bf2f(u.y), t2 = bf2f(u.z), t3 = bf2f(u.w);
        #pragma unroll
        for (int r = 0; r < 9; ++r) {
          int i = jy + 32 * r;
          if (i < n) {
            float a = sm_xa[i * 34 + jj];
            acc[r][0] += a * t0; acc[r][1] += a * t1;
            acc[r][2] += a * t2; acc[r][3] += a * t3;
          }
        }
      }
    }
    __syncthreads();
  }
  const float inv3 = 1.f / 3.f;
  float4 bq = *(const float4*)(bias + c0 + cc);
  #pragma unroll
  for (int r = 0; r < 9; ++r) {
    int i = jy + 32 * r;
    if (i < n) {
      ushort4 u;
      u.x = f2bf(acc[r][0] * inv3 + bq.x);
      u.y = f2bf(acc[r][1] * inv3 + bq.y);
      u.z = f2bf(acc[r][2] * inv3 + bq.z);
      u.w = f2bf(acc[r][3] * inv3 + bq.w);
      *(ushort4*)(xout + (size_t)(ob + i) * C + c0 + cc) = u;
    }
  }
}

// ---------------- pad-row value after layer 2 ----------------
__global__ __launch_bounds__(256) void k_pad(
    const float* __restrict__ b1, const float* __restrict__ W2,
    const float* __restrict__ b2g, float* __restrict__ pad2) {
  int c = threadIdx.x;  // 256
  float s = 0.f;
  for (int h = 0; h < 3; ++h)
    for (int k = 0; k < C1; ++k)
      s += b1[k] * W2[(size_t)k * (3 * C2) + h * C2 + c];
  pad2[c] = s * (1.f / 3.f) + b2g[c];
}

// ---------------- readout: comp_x + concat ----------------
__global__ __launch_bounds__(256) void k_feat2(
    const unsigned short* __restrict__ x2, const float* __restrict__ pad2,
    const int* __restrict__ off, const int* __restrict__ natoms,
    const float* __restrict__ sgx, const float* __restrict__ latx,
    float* __restrict__ feat) {
  int b = blockIdx.x, tid = threadIdx.x;
  int n = natoms[b], ob = off[b];
  float s = (float)(NMAX - n) * pad2[tid];
  for (int i = 0; i < n; ++i) s += bf2f(x2[(size_t)(ob + i) * C2 + tid]);
  feat[b * PIN + tid] = s;
  if (tid < SGE) feat[b * PIN + 256 + tid] = sgx[b * SGE + tid];
  if (tid < LATH) feat[b * PIN + 320 + tid] = latx[b * LATH + tid];
}

// ---------------- head MLP ----------------
__global__ __launch_bounds__(256) void k_head(
    const float* __restrict__ feat,
    const float* __restrict__ W1, const float* __restrict__ b1,
    const float* __restrict__ g1, const float* __restrict__ be1,
    const float* __restrict__ m1, const float* __restrict__ v1,
    const float* __restrict__ W2, const float* __restrict__ b2,
    const float* __restrict__ g2, const float* __restrict__ be2,
    const float* __restrict__ m2, const float* __restrict__ v2,
    const float* __restrict__ W3, const float* __restrict__ b3,
    float* __restrict__ out) {
  int b = blockIdx.x, tid = threadIdx.x;
  __shared__ float f[PIN];
  __shared__ float h1[P1];
  __shared__ float h2[P1];
  __shared__ float red[256];
  for (int i = tid; i < PIN; i += 256) f[i] = feat[b * PIN + i];
  __syncthreads();
  for (int o = tid; o < P1; o += 256) {
    float acc = b1[o];
    for (int k = 0; k < PIN; ++k) acc += f[k] * W1[k * P1 + o];
    acc = (acc - m1[o]) * g1[o] * rsqrtf(v1[o] + EPSB) + be1[o];
    h1[o] = acc >= 0.f ? acc : 0.2f * acc;
  }
  __syncthreads();
  for (int o = tid; o < P1; o += 256) {
    float acc = b2[o];
    for (int k = 0; k < P1; ++k) acc += h1[k] * W2[k * P1 + o];
    acc = (acc - m2[o]) * g2[o] * rsqrtf(v2[o] + EPSB) + be2[o];
    h2[o] = acc >= 0.f ? acc : 0.2f * acc;
  }
  __syncthreads();
  float p = 0.f;
  for (int k = tid; k < P1; k += 256) p += h2[k] * W3[k];
  red[tid] = p;
  __syncthreads();
  for (int s = 128; s > 0; s >>= 1) {
    if (tid < s) red[tid] += red[tid + s];
    __syncthreads();
  }
  if (tid == 0) out[b] = red[0] + b3[0];
}

extern "C" void kernel_launch(void* const* d_in, const int* in_sizes, int n_in,
                              void* d_out, int out_size, void* d_ws, size_t ws_size,
                              hipStream_t stream) {
  const int*   comp       = (const int*)d_in[0];
  const int*   sg         = (const int*)d_in[1];
  const float* lat        = (const float*)d_in[2];
  const int*   period_idx = (const int*)d_in[3];
  const int*   group_idx  = (const int*)d_in[4];
  const float* sg_emb     = (const float*)d_in[5];
  const float* lat_W1     = (const float*)d_in[6];
  const float* lat_b1     = (const float*)d_in[7];
  const float* lat_bn1_g  = (const float*)d_in[8];
  const float* lat_bn1_b  = (const float*)d_in[9];
  const float* lat_bn1_m  = (const float*)d_in[10];
  const float* lat_bn1_v  = (const float*)d_in[11];
  const float* lat_W2     = (const float*)d_in[12];
  const float* lat_b2     = (const float*)d_in[13];
  const float* lat_bn2_g  = (const float*)d_in[14];
  const float* lat_bn2_b  = (const float*)d_in[15];
  const float* lat_bn2_m  = (const float*)d_in[16];
  const float* lat_bn2_v  = (const float*)d_in[17];
  const float* z_emb      = (const float*)d_in[18];
  const float* period_t   = (const float*)d_in[19];
  const float* group_t    = (const float*)d_in[20];
  const float* props      = (const float*)d_in[21];
  const float* W_props    = (const float*)d_in[22];
  const float* b_props    = (const float*)d_in[23];
  const float* W_phys     = (const float*)d_in[24];
  const float* b_phys     = (const float*)d_in[25];
  const float* gat1_W     = (const float*)d_in[26];
  const float* gat1_as    = (const float*)d_in[27];
  const float* gat1_ad    = (const float*)d_in[28];
  const float* gat1_b     = (const float*)d_in[29];
  const float* gat2_W     = (const float*)d_in[30];
  const float* gat2_as    = (const float*)d_in[31];
  const float* gat2_ad    = (const float*)d_in[32];
  const float* gat2_b     = (const float*)d_in[33];
  const float* pW1        = (const float*)d_in[34];
  const float* pb1        = (const float*)d_in[35];
  const float* pbn1_g     = (const float*)d_in[36];
  const float* pbn1_b     = (const float*)d_in[37];
  const float* pbn1_m     = (const float*)d_in[38];
  const float* pbn1_v     = (const float*)d_in[39];
  const float* pW2        = (const float*)d_in[40];
  const float* pb2        = (const float*)d_in[41];
  const float* pbn2_g     = (const float*)d_in[42];
  const float* pbn2_b     = (const float*)d_in[43];
  const float* pbn2_m     = (const float*)d_in[44];
  const float* pbn2_v     = (const float*)d_in[45];
  const float* pW3        = (const float*)d_in[46];
  const float* pb3        = (const float*)d_in[47];

  float* ws = (float*)d_ws;
  const size_t o_sgx  = 0;
  const size_t o_latx = o_sgx  + (size_t)BB * SGE;            // 16384
  const size_t o_nat  = o_latx + (size_t)BB * LATH;           // 49152
  const size_t o_off  = o_nat  + BB;                          // 49408
  const size_t o_z    = o_off  + BB;                          // 49664
  const size_t o_phys = o_z    + (size_t)BB * NMAX;           // 118784
  const size_t o_wsv  = o_phys + (size_t)NEL * 256;           // 141824
  const size_t o_wdv  = o_wsv  + (size_t)C1 * 3;              // 143168
  const size_t o_asrc = o_wdv  + (size_t)C1 * 3;              // 144512
  const size_t o_adst = o_asrc + (size_t)BB * NMAX * 3;
  const size_t o_rm   = o_adst + (size_t)BB * NMAX * 3;
  const size_t o_rs   = o_rm   + (size_t)BB * NMAX * 3;
  const size_t o_pad2 = o_rs   + (size_t)BB * NMAX * 3;
  const size_t o_x0   = o_pad2 + 256;                         // bf16 region (x0, then x2)
  const size_t o_x1   = o_x0   + (size_t)BB * NMAX * PIN / 2; // bf16 region (x1, then feat)

  float* sgx    = ws + o_sgx;
  float* latx   = ws + o_latx;
  int*   natoms = (int*)(ws + o_nat);
  int*   off    = (int*)(ws + o_off);
  int*   z      = (int*)(ws + o_z);
  float* physpe = ws + o_phys;
  float* wsv    = ws + o_wsv;
  float* wdv    = ws + o_wdv;
  float* asrc   = ws + o_asrc;
  float* adst   = ws + o_adst;
  float* rowm   = ws + o_rm;
  float* rows   = ws + o_rs;
  float* pad2   = ws + o_pad2;
  unsigned short* x0 = (unsigned short*)(ws + o_x0);  // [total,448]
  unsigned short* x1 = (unsigned short*)(ws + o_x1);  // [total,448]
  unsigned short* x2 = x0;                            // [total,256] reuse
  float* feat   = ws + o_x1;                          // reuse x1 region after layer 2

  k_prep<<<BB, 256, 0, stream>>>(comp, sg, lat, sg_emb,
      lat_W1, lat_b1, lat_bn1_g, lat_bn1_b, lat_bn1_m, lat_bn1_v,
      lat_W2, lat_b2, lat_bn2_g, lat_bn2_b, lat_bn2_m, lat_bn2_v,
      sgx, latx, z, natoms);
  k_scan<<<1, 256, 0, stream>>>(natoms, off);
  k_physpe<<<NEL, 256, 0, stream>>>(period_idx, group_idx, z_emb, period_t, group_t,
      props, W_props, b_props, W_phys, b_phys, physpe);
  k_nodep<<<BB, 256, 0, stream>>>(z, off, natoms, physpe, latx, sgx, x0);

  // ---- GAT layer 1 ----
  k_fold<<<C1, 64, 0, stream>>>(gat1_W, gat1_as, gat1_ad, 3 * C1, C1, wsv, wdv);
  k_av2<<<BB * NMAX, 64, 0, stream>>>(x0, wsv, wdv, off, natoms, asrc, adst, PIN);
  k_stats2<<<BB, 256, 0, stream>>>(asrc, adst, off, natoms, rowm, rows);
  k_fused<<<dim3(C1 / 32, BB), 256, 0, stream>>>(x0, gat1_W, asrc, adst, rowm, rows,
      off, natoms, gat1_b, x1, PIN, C1, 3 * C1);

  // ---- GAT layer 2 ----
  k_fold<<<C1, 64, 0, stream>>>(gat2_W, gat2_as, gat2_ad, 3 * C2, C2, wsv, wdv);
  k_av2<<<BB * NMAX, 64, 0, stream>>>(x1, wsv, wdv, off, natoms, asrc, adst, C1);
  k_stats2<<<BB, 256, 0, stream>>>(asrc, adst, off, natoms, rowm, rows);
  k_pad<<<1, 256, 0, stream>>>(gat1_b, gat2_W, gat2_b, pad2);
  k_fused<<<dim3(C2 / 32, BB), 256, 0, stream>>>(x1, gat2_W, asrc, adst, rowm, rows,
      off, natoms, gat2_b, x2, C1, C2, 3 * C2);

  // ---- readout + head ----
  k_feat2<<<BB, 256, 0, stream>>>(x2, pad2, off, natoms, sgx, latx, feat);
  k_head<<<BB, 256, 0, stream>>>(feat,
      pW1, pb1, pbn1_g, pbn1_b, pbn1_m, pbn1_v,
      pW2, pb2, pbn2_g, pbn2_b, pbn2_m, pbn2_v,
      pW3, pb3, (float*)d_out);
}

// Round 3
// 2518.842 us; speedup vs baseline: 2.9558x; 2.9558x over previous
//
#include <hip/hip_runtime.h>
#include <math.h>

#define BB 256
#define NEL 90
#define NMAX 270
#define C1 448
#define C2 256
#define PIN 448
#define LATH 128
#define SGE 64
#define P1 512
#define EPSB 1e-5f

typedef short shortx8 __attribute__((ext_vector_type(8)));
typedef float floatx4 __attribute__((ext_vector_type(4)));

__device__ __forceinline__ float bf2f(unsigned short u) {
  return __uint_as_float(((unsigned)u) << 16);
}
__device__ __forceinline__ unsigned short f2bf(float f) {
  unsigned x = __float_as_uint(f);
  unsigned r = (x + 0x7fffu + ((x >> 16) & 1u)) >> 16;
  return (unsigned short)r;
}

// ---------------- prep: cumsum -> z, n_atoms, sg_x, lat MLP ----------------
__global__ __launch_bounds__(256) void k_prep(
    const int* __restrict__ comp, const int* __restrict__ sg, const float* __restrict__ lat,
    const float* __restrict__ sg_emb,
    const float* __restrict__ W1, const float* __restrict__ b1,
    const float* __restrict__ g1, const float* __restrict__ be1,
    const float* __restrict__ m1, const float* __restrict__ v1,
    const float* __restrict__ W2, const float* __restrict__ b2,
    const float* __restrict__ g2, const float* __restrict__ be2,
    const float* __restrict__ m2, const float* __restrict__ v2,
    float* __restrict__ sgx, float* __restrict__ latx,
    int* __restrict__ z, int* __restrict__ natoms) {
  int b = blockIdx.x;
  int tid = threadIdx.x;
  __shared__ int cum[NEL];
  __shared__ float hbuf[LATH];
  __shared__ float latl[6];
  if (tid == 0) {
    int s = 0;
    for (int e = 0; e < NEL; ++e) { s += comp[b * NEL + e]; cum[e] = s; }
    natoms[b] = s;
  }
  if (tid < 6) latl[tid] = lat[b * 6 + tid];
  __syncthreads();
  int n = cum[NEL - 1];
  for (int t = tid; t < NMAX; t += blockDim.x) {
    int zz = -1;
    if (t < n) {
      for (int e = 0; e < NEL; ++e) { if (cum[e] > t) { zz = e; break; } }
    }
    z[b * NMAX + t] = zz;
  }
  if (tid < SGE) {
    int si = sg[b];
    sgx[b * SGE + tid] = sg_emb[si * SGE + tid];
  }
  if (tid < LATH) {
    float acc = b1[tid];
    for (int k = 0; k < 6; ++k) acc += latl[k] * W1[k * LATH + tid];
    acc = (acc - m1[tid]) * g1[tid] * rsqrtf(v1[tid] + EPSB) + be1[tid];
    hbuf[tid] = acc;
  }
  __syncthreads();
  if (tid < LATH) {
    float acc = b2[tid];
    for (int k = 0; k < LATH; ++k) acc += hbuf[k] * W2[k * LATH + tid];
    acc = (acc - m2[tid]) * g2[tid] * rsqrtf(v2[tid] + EPSB) + be2[tid];
    latx[b * LATH + tid] = acc;
  }
}

// ---------------- exclusive scan of natoms -> off ----------------
__global__ __launch_bounds__(256) void k_scan(const int* __restrict__ natoms,
                                              int* __restrict__ off) {
  __shared__ int sh[BB];
  int tid = threadIdx.x;
  int v0 = natoms[tid];
  sh[tid] = v0;
  for (int d = 1; d < BB; d <<= 1) {
    __syncthreads();
    int v = (tid >= d) ? sh[tid - d] : 0;
    __syncthreads();
    sh[tid] += v;
  }
  __syncthreads();
  off[tid] = sh[tid] - v0;
}

// ---------------- per-element-type phys rows: [90,256] ----------------
__global__ __launch_bounds__(256) void k_physpe(
    const int* __restrict__ period_idx, const int* __restrict__ group_idx,
    const float* __restrict__ z_emb, const float* __restrict__ period_t,
    const float* __restrict__ group_t, const float* __restrict__ props,
    const float* __restrict__ Wp, const float* __restrict__ bp,
    const float* __restrict__ Wphys, const float* __restrict__ bphys,
    float* __restrict__ physpe) {
  int e = blockIdx.x;
  int tid = threadIdx.x;
  __shared__ float ph[128];
  if (tid < 32) ph[tid] = z_emb[e * 32 + tid];
  else if (tid < 64) ph[tid] = period_t[period_idx[e] * 32 + tid - 32];
  else if (tid < 96) ph[tid] = group_t[group_idx[e] * 32 + tid - 64];
  else if (tid < 128) {
    int j = tid - 96;
    float acc = bp[j];
    for (int k = 0; k < 20; ++k) acc += props[e * 20 + k] * Wp[k * 32 + j];
    ph[tid] = acc;
  }
  __syncthreads();
  float acc = bphys[tid];
  for (int k = 0; k < 128; ++k) acc += ph[k] * Wphys[k * 256 + tid];
  physpe[e * 256 + tid] = acc;
}

// ---------------- packed node features x0 [total,448] bf16 ----------------
__global__ __launch_bounds__(256) void k_nodep(
    const int* __restrict__ z, const int* __restrict__ off, const int* __restrict__ natoms,
    const float* __restrict__ physpe, const float* __restrict__ latx,
    const float* __restrict__ sgx, unsigned short* __restrict__ x0) {
  int b = blockIdx.x;
  int n = natoms[b], ob = off[b];
  int tid = threadIdx.x;
  for (int e = tid; e < n * PIN; e += 256) {
    int t = e / PIN, c = e % PIN;
    int zt = z[b * NMAX + t];
    float v = (c < 256) ? physpe[zt * 256 + c]
            : (c < 384) ? latx[b * LATH + (c - 256)]
                        : sgx[b * SGE + (c - 384)];
    x0[(size_t)(ob + t) * PIN + c] = f2bf(v);
  }
}

// ---------------- W [K][3C] fp32 -> Wt [3C][K] bf16 (tile transpose) -------
__global__ __launch_bounds__(256) void k_wprep(
    const float* __restrict__ W, unsigned short* __restrict__ Wt, int K, int NC3) {
  int k0 = blockIdx.x << 5;
  int c0 = blockIdx.y << 5;
  __shared__ float ts[32][33];
  int e = threadIdx.x << 2;
  int kk = e >> 5, cc = e & 31;
  float4 v = *(const float4*)(W + (size_t)(k0 + kk) * NC3 + c0 + cc);
  ts[kk][cc] = v.x; ts[kk][cc + 1] = v.y; ts[kk][cc + 2] = v.z; ts[kk][cc + 3] = v.w;
  __syncthreads();
  int c2 = threadIdx.x & 31, kg = threadIdx.x >> 5;
  ushort4 u;
  u.x = f2bf(ts[kg * 4 + 0][c2]); u.y = f2bf(ts[kg * 4 + 1][c2]);
  u.z = f2bf(ts[kg * 4 + 2][c2]); u.w = f2bf(ts[kg * 4 + 3][c2]);
  *(ushort4*)(Wt + (size_t)(c0 + c2) * K + k0 + (kg << 2)) = u;
}

// ---------------- fold a_s/a_d through W: wsv/wdv [K][3] ----------------
__global__ __launch_bounds__(64) void k_fold(
    const float* __restrict__ W, const float* __restrict__ a_s, const float* __restrict__ a_d,
    int NC3, int C, float* __restrict__ wsv, float* __restrict__ wdv) {
  int k = blockIdx.x;
  int tid = threadIdx.x;
  for (int h = 0; h < 3; ++h) {
    float ss = 0.f, sd = 0.f;
    for (int c = tid; c < C; c += 64) {
      float wv = W[(size_t)k * NC3 + h * C + c];
      ss += wv * a_s[h * C + c];
      sd += wv * a_d[h * C + c];
    }
    for (int o = 32; o > 0; o >>= 1) { ss += __shfl_down(ss, o); sd += __shfl_down(sd, o); }
    if (tid == 0) { wsv[k * 3 + h] = ss; wdv[k * 3 + h] = sd; }
  }
}

// ---------------- asrc/adst for packed rows ----------------
__global__ __launch_bounds__(64) void k_av2(
    const unsigned short* __restrict__ x, const float* __restrict__ wsv,
    const float* __restrict__ wdv, const int* __restrict__ off,
    const int* __restrict__ natoms, float* __restrict__ asrc,
    float* __restrict__ adst, int K) {
  int row = blockIdx.x;
  int total = off[BB - 1] + natoms[BB - 1];
  if (row >= total) return;
  int tid = threadIdx.x;
  float s0 = 0.f, s1 = 0.f, s2 = 0.f, d0 = 0.f, d1 = 0.f, d2 = 0.f;
  for (int k = tid; k < K; k += 64) {
    float xv = bf2f(x[(size_t)row * K + k]);
    s0 += xv * wsv[k * 3 + 0]; s1 += xv * wsv[k * 3 + 1]; s2 += xv * wsv[k * 3 + 2];
    d0 += xv * wdv[k * 3 + 0]; d1 += xv * wdv[k * 3 + 1]; d2 += xv * wdv[k * 3 + 2];
  }
  for (int o = 32; o > 0; o >>= 1) {
    s0 += __shfl_down(s0, o); s1 += __shfl_down(s1, o); s2 += __shfl_down(s2, o);
    d0 += __shfl_down(d0, o); d1 += __shfl_down(d1, o); d2 += __shfl_down(d2, o);
  }
  if (tid == 0) {
    asrc[row * 3 + 0] = s0; asrc[row * 3 + 1] = s1; asrc[row * 3 + 2] = s2;
    adst[row * 3 + 0] = d0; adst[row * 3 + 1] = d1; adst[row * 3 + 2] = d2;
  }
}

// ---------------- per-row softmax stats (packed, j<n) ----------------
__global__ __launch_bounds__(256) void k_stats2(
    const float* __restrict__ asrc, const float* __restrict__ adst,
    const int* __restrict__ off, const int* __restrict__ natoms,
    float* __restrict__ rowm, float* __restrict__ rowsum) {
  int b = blockIdx.x;
  int n = natoms[b], ob = off[b];
  __shared__ float as_l[NMAX * 3];
  int tid = threadIdx.x;
  for (int e = tid; e < n * 3; e += 256) as_l[e] = asrc[ob * 3 + e];
  __syncthreads();
  for (int i = tid; i < n; i += 256) {
    for (int h = 0; h < 3; ++h) {
      float adv = adst[(ob + i) * 3 + h];
      float m = -1e30f;
      for (int j = 0; j < n; ++j) {
        float sc = as_l[j * 3 + h] + adv;
        sc = sc >= 0.f ? sc : 0.2f * sc;
        m = fmaxf(m, sc);
      }
      float s = 0.f;
      for (int j = 0; j < n; ++j) {
        float sc = as_l[j * 3 + h] + adv;
        sc = sc >= 0.f ? sc : 0.2f * sc;
        s += __expf(sc - m);
      }
      rowm[(ob + i) * 3 + h] = m;
      rowsum[(ob + i) * 3 + h] = s;
    }
  }
}

// ---------------- fused MFMA GAT layer ----------------
// grid: 1D NC*256 blocks, swizzled so a graph's col-blocks share bid%8 (XCD).
// Phase 1: t[j][c-tile 32] = x @ W_h (MFMA, A from LDS xs, B from LDS W^T tile)
// Phase 2: acc += alpha_h @ t (alpha built in-register in A-frag layout)
#define XSS 40   // xs row stride (bf16): 80 B -> conflict-free b128 A-frags
#define TTS 296  // t^T row stride (bf16): 592 B

__global__ __launch_bounds__(256, 3) void k_fused_mfma(
    const unsigned short* __restrict__ xin, const unsigned short* __restrict__ Wt,
    const float* __restrict__ asrc, const float* __restrict__ adst,
    const float* __restrict__ rowm, const float* __restrict__ rowsum,
    const int* __restrict__ off, const int* __restrict__ natoms,
    const float* __restrict__ bias, unsigned short* __restrict__ xout,
    int K, int C, int NC) {
  int bid = blockIdx.x;
  int xg = bid & 7;
  int g = bid >> 3;
  int cblk = g % NC;
  int b = xg + ((g / NC) << 3);
  int c0 = cblk << 5;
  int n = natoms[b];
  int ob = off[b];
  int tid = threadIdx.x;
  int wv = tid >> 6;
  int lane = tid & 63;
  int m16 = lane & 15;
  int q = lane >> 4;

  int mtn = (n + 15) >> 4;   // 16-row M tiles
  int jmax = mtn << 4;
  int ktn = (n + 31) >> 5;   // phase-2 K steps
  int kext = ktn << 5;

  __shared__ unsigned short xs[272 * XSS];   // 21.75 KB
  __shared__ unsigned short tt[32 * TTS];    // 18.5 KB (overlaid by wt_s in phase 1)
  __shared__ float sm_as[288], sm_ad[288], sm_m[288], sm_rs[288];  // 4.5 KB
  unsigned short* wt_s = tt;

  floatx4 acc[5][2];
  #pragma unroll
  for (int i = 0; i < 5; ++i) { acc[i][0] = (floatx4)0.f; acc[i][1] = (floatx4)0.f; }

  for (int h = 0; h < 3; ++h) {
    __syncthreads();  // prev head's phase-2 reads done
    for (int i2 = tid; i2 < kext; i2 += 256) {
      bool v = i2 < n;
      sm_as[i2] = v ? asrc[(ob + i2) * 3 + h] : 0.f;
      sm_ad[i2] = v ? adst[(ob + i2) * 3 + h] : 0.f;
      sm_m[i2]  = v ? rowm[(ob + i2) * 3 + h] : 0.f;
      sm_rs[i2] = v ? 1.f / rowsum[(ob + i2) * 3 + h] : 0.f;
    }
    floatx4 tac[5][2];
    #pragma unroll
    for (int i = 0; i < 5; ++i) { tac[i][0] = (floatx4)0.f; tac[i][1] = (floatx4)0.f; }

    for (int k0 = 0; k0 < K; k0 += 32) {
      __syncthreads();
      // stage x tile [jmax][32] bf16 (zero rows >= n)
      for (int e = tid * 8; e < (jmax << 5); e += 2048) {
        int j = e >> 5, kk = e & 31;
        uint4 v = make_uint4(0u, 0u, 0u, 0u);
        if (j < n) v = *(const uint4*)(xin + (size_t)(ob + j) * K + k0 + kk);
        *(uint4*)(xs + j * XSS + kk) = v;
      }
      // stage W^T tile [32 c][32 k]
      {
        int r = tid >> 3, kk = (tid & 7) << 2;
        ushort4 wv4 = *(const ushort4*)(Wt + (size_t)(h * C + c0 + r) * K + k0 + kk);
        *(ushort4*)(wt_s + r * XSS + kk) = wv4;
      }
      __syncthreads();
      shortx8 b0 = *(const shortx8*)(wt_s + m16 * XSS + (q << 3));
      shortx8 b1 = *(const shortx8*)(wt_s + (16 + m16) * XSS + (q << 3));
      int t_i = 0;
      for (int mt = wv; mt < mtn; mt += 4, ++t_i) {
        shortx8 a = *(const shortx8*)(xs + ((mt << 4) + m16) * XSS + (q << 3));
        tac[t_i][0] = __builtin_amdgcn_mfma_f32_16x16x32_bf16(a, b0, tac[t_i][0], 0, 0, 0);
        tac[t_i][1] = __builtin_amdgcn_mfma_f32_16x16x32_bf16(a, b1, tac[t_i][1], 0, 0, 0);
      }
    }
    __syncthreads();  // all waves done with wt_s
    // write t^T (cols c -> rows of tt, contiguous in j)
    {
      int t_i = 0;
      for (int mt = wv; mt < mtn; mt += 4, ++t_i) {
        int jr = (mt << 4) + (q << 2);
        #pragma unroll
        for (int nt = 0; nt < 2; ++nt) {
          floatx4 d = tac[t_i][nt];
          ushort4 u;
          u.x = f2bf(d.x); u.y = f2bf(d.y); u.z = f2bf(d.z); u.w = f2bf(d.w);
          *(ushort4*)(tt + ((nt << 4) + m16) * TTS + jr) = u;
        }
      }
      int span = kext - jmax;
      for (int e = tid; e < (span << 5); e += 256) {
        int c = e / span, j = jmax + (e % span);
        tt[c * TTS + j] = 0;
      }
    }
    __syncthreads();  // tt ready
    // phase 2: acc += alpha_h @ t
    {
      float adr[5], mr[5], rsr[5];
      int ntl = 0;
      for (int mt = wv; mt < mtn; mt += 4, ++ntl) {
        int i = (mt << 4) + m16;
        adr[ntl] = sm_ad[i]; mr[ntl] = sm_m[i]; rsr[ntl] = sm_rs[i];
      }
      for (int k0p = 0; k0p < kext; k0p += 32) {
        shortx8 tb0 = *(const shortx8*)(tt + m16 * TTS + k0p + (q << 3));
        shortx8 tb1 = *(const shortx8*)(tt + (16 + m16) * TTS + k0p + (q << 3));
        float asj[8];
        #pragma unroll
        for (int j8 = 0; j8 < 8; ++j8) asj[j8] = sm_as[k0p + (q << 3) + j8];
        int t2 = 0;
        for (int mt = wv; mt < mtn; mt += 4, ++t2) {
          shortx8 af;
          #pragma unroll
          for (int j8 = 0; j8 < 8; ++j8) {
            int j = k0p + (q << 3) + j8;
            float sc = asj[j8] + adr[t2];
            sc = fmaxf(sc, 0.2f * sc);
            float al = __expf(sc - mr[t2]) * rsr[t2];
            af[j8] = (short)f2bf(j < n ? al : 0.f);
          }
          acc[t2][0] = __builtin_amdgcn_mfma_f32_16x16x32_bf16(af, tb0, acc[t2][0], 0, 0, 0);
          acc[t2][1] = __builtin_amdgcn_mfma_f32_16x16x32_bf16(af, tb1, acc[t2][1], 0, 0, 0);
        }
      }
    }
  }
  // epilogue: mean over heads + bias, write bf16
  float bq0 = bias[c0 + m16];
  float bq1 = bias[c0 + 16 + m16];
  const float inv3 = 1.f / 3.f;
  int t_i = 0;
  for (int mt = wv; mt < mtn; mt += 4, ++t_i) {
    #pragma unroll
    for (int nt = 0; nt < 2; ++nt) {
      floatx4 d = acc[t_i][nt];
      float bq = nt ? bq1 : bq0;
      int cidx = c0 + (nt << 4) + m16;
      #pragma unroll
      for (int r = 0; r < 4; ++r) {
        int i = (mt << 4) + (q << 2) + r;
        if (i < n) xout[(size_t)(ob + i) * C + cidx] = f2bf(d[r] * inv3 + bq);
      }
    }
  }
}

// ---------------- pad-row value after layer 2 ----------------
__global__ __launch_bounds__(256) void k_pad(
    const float* __restrict__ b1, const float* __restrict__ W2,
    const float* __restrict__ b2g, float* __restrict__ pad2) {
  int c = threadIdx.x;  // 256
  float s = 0.f;
  for (int h = 0; h < 3; ++h)
    for (int k = 0; k < C1; ++k)
      s += b1[k] * W2[(size_t)k * (3 * C2) + h * C2 + c];
  pad2[c] = s * (1.f / 3.f) + b2g[c];
}

// ---------------- readout: comp_x + concat ----------------
__global__ __launch_bounds__(256) void k_feat2(
    const unsigned short* __restrict__ x2, const float* __restrict__ pad2,
    const int* __restrict__ off, const int* __restrict__ natoms,
    const float* __restrict__ sgx, const float* __restrict__ latx,
    float* __restrict__ feat) {
  int b = blockIdx.x, tid = threadIdx.x;
  int n = natoms[b], ob = off[b];
  float s = (float)(NMAX - n) * pad2[tid];
  for (int i = 0; i < n; ++i) s += bf2f(x2[(size_t)(ob + i) * C2 + tid]);
  feat[b * PIN + tid] = s;
  if (tid < SGE) feat[b * PIN + 256 + tid] = sgx[b * SGE + tid];
  if (tid < LATH) feat[b * PIN + 320 + tid] = latx[b * LATH + tid];
}

// ---------------- head MLP ----------------
__global__ __launch_bounds__(256) void k_head(
    const float* __restrict__ feat,
    const float* __restrict__ W1, const float* __restrict__ b1,
    const float* __restrict__ g1, const float* __restrict__ be1,
    const float* __restrict__ m1, const float* __restrict__ v1,
    const float* __restrict__ W2, const float* __restrict__ b2,
    const float* __restrict__ g2, const float* __restrict__ be2,
    const float* __restrict__ m2, const float* __restrict__ v2,
    const float* __restrict__ W3, const float* __restrict__ b3,
    float* __restrict__ out) {
  int b = blockIdx.x, tid = threadIdx.x;
  __shared__ float f[PIN];
  __shared__ float h1[P1];
  __shared__ float h2[P1];
  __shared__ float red[256];
  for (int i = tid; i < PIN; i += 256) f[i] = feat[b * PIN + i];
  __syncthreads();
  for (int o = tid; o < P1; o += 256) {
    float acc = b1[o];
    for (int k = 0; k < PIN; ++k) acc += f[k] * W1[k * P1 + o];
    acc = (acc - m1[o]) * g1[o] * rsqrtf(v1[o] + EPSB) + be1[o];
    h1[o] = acc >= 0.f ? acc : 0.2f * acc;
  }
  __syncthreads();
  for (int o = tid; o < P1; o += 256) {
    float acc = b2[o];
    for (int k = 0; k < P1; ++k) acc += h1[k] * W2[k * P1 + o];
    acc = (acc - m2[o]) * g2[o] * rsqrtf(v2[o] + EPSB) + be2[o];
    h2[o] = acc >= 0.f ? acc : 0.2f * acc;
  }
  __syncthreads();
  float p = 0.f;
  for (int k = tid; k < P1; k += 256) p += h2[k] * W3[k];
  red[tid] = p;
  __syncthreads();
  for (int s = 128; s > 0; s >>= 1) {
    if (tid < s) red[tid] += red[tid + s];
    __syncthreads();
  }
  if (tid == 0) out[b] = red[0] + b3[0];
}

extern "C" void kernel_launch(void* const* d_in, const int* in_sizes, int n_in,
                              void* d_out, int out_size, void* d_ws, size_t ws_size,
                              hipStream_t stream) {
  const int*   comp       = (const int*)d_in[0];
  const int*   sg         = (const int*)d_in[1];
  const float* lat        = (const float*)d_in[2];
  const int*   period_idx = (const int*)d_in[3];
  const int*   group_idx  = (const int*)d_in[4];
  const float* sg_emb     = (const float*)d_in[5];
  const float* lat_W1     = (const float*)d_in[6];
  const float* lat_b1     = (const float*)d_in[7];
  const float* lat_bn1_g  = (const float*)d_in[8];
  const float* lat_bn1_b  = (const float*)d_in[9];
  const float* lat_bn1_m  = (const float*)d_in[10];
  const float* lat_bn1_v  = (const float*)d_in[11];
  const float* lat_W2     = (const float*)d_in[12];
  const float* lat_b2     = (const float*)d_in[13];
  const float* lat_bn2_g  = (const float*)d_in[14];
  const float* lat_bn2_b  = (const float*)d_in[15];
  const float* lat_bn2_m  = (const float*)d_in[16];
  const float* lat_bn2_v  = (const float*)d_in[17];
  const float* z_emb      = (const float*)d_in[18];
  const float* period_t   = (const float*)d_in[19];
  const float* group_t    = (const float*)d_in[20];
  const float* props      = (const float*)d_in[21];
  const float* W_props    = (const float*)d_in[22];
  const float* b_props    = (const float*)d_in[23];
  const float* W_phys     = (const float*)d_in[24];
  const float* b_phys     = (const float*)d_in[25];
  const float* gat1_W     = (const float*)d_in[26];
  const float* gat1_as    = (const float*)d_in[27];
  const float* gat1_ad    = (const float*)d_in[28];
  const float* gat1_b     = (const float*)d_in[29];
  const float* gat2_W     = (const float*)d_in[30];
  const float* gat2_as    = (const float*)d_in[31];
  const float* gat2_ad    = (const float*)d_in[32];
  const float* gat2_b     = (const float*)d_in[33];
  const float* pW1        = (const float*)d_in[34];
  const float* pb1        = (const float*)d_in[35];
  const float* pbn1_g     = (const float*)d_in[36];
  const float* pbn1_b     = (const float*)d_in[37];
  const float* pbn1_m     = (const float*)d_in[38];
  const float* pbn1_v     = (const float*)d_in[39];
  const float* pW2        = (const float*)d_in[40];
  const float* pb2        = (const float*)d_in[41];
  const float* pbn2_g     = (const float*)d_in[42];
  const float* pbn2_b     = (const float*)d_in[43];
  const float* pbn2_m     = (const float*)d_in[44];
  const float* pbn2_v     = (const float*)d_in[45];
  const float* pW3        = (const float*)d_in[46];
  const float* pb3        = (const float*)d_in[47];

  float* ws = (float*)d_ws;
  const size_t o_sgx  = 0;
  const size_t o_latx = o_sgx  + (size_t)BB * SGE;
  const size_t o_nat  = o_latx + (size_t)BB * LATH;
  const size_t o_off  = o_nat  + BB;
  const size_t o_z    = o_off  + BB;
  const size_t o_phys = o_z    + (size_t)BB * NMAX;
  const size_t o_wsv  = o_phys + (size_t)NEL * 256;
  const size_t o_wdv  = o_wsv  + (size_t)C1 * 3;
  const size_t o_asrc = o_wdv  + (size_t)C1 * 3;
  const size_t o_adst = o_asrc + (size_t)BB * NMAX * 3;
  const size_t o_rm   = o_adst + (size_t)BB * NMAX * 3;
  const size_t o_rs   = o_rm   + (size_t)BB * NMAX * 3;
  const size_t o_pad2 = o_rs   + (size_t)BB * NMAX * 3;
  const size_t o_wt1  = o_pad2 + 256;
  const size_t o_wt2  = o_wt1  + (size_t)(3 * C1) * PIN / 2;  // bf16 region
  const size_t o_x0   = o_wt2  + (size_t)(3 * C2) * C1 / 2;   // bf16 region
  const size_t o_x1   = o_x0   + (size_t)BB * NMAX * PIN / 2;

  float* sgx    = ws + o_sgx;
  float* latx   = ws + o_latx;
  int*   natoms = (int*)(ws + o_nat);
  int*   off    = (int*)(ws + o_off);
  int*   z      = (int*)(ws + o_z);
  float* physpe = ws + o_phys;
  float* wsv    = ws + o_wsv;
  float* wdv    = ws + o_wdv;
  float* asrc   = ws + o_asrc;
  float* adst   = ws + o_adst;
  float* rowm   = ws + o_rm;
  float* rows   = ws + o_rs;
  float* pad2   = ws + o_pad2;
  unsigned short* wt1 = (unsigned short*)(ws + o_wt1);  // [1344,448] bf16
  unsigned short* wt2 = (unsigned short*)(ws + o_wt2);  // [768,448] bf16
  unsigned short* x0  = (unsigned short*)(ws + o_x0);   // [total,448] bf16
  unsigned short* x1  = (unsigned short*)(ws + o_x1);   // [total,448] bf16
  unsigned short* x2  = x0;                              // [total,256] reuse
  float* feat   = ws + o_x1;                             // reuse after layer 2

  k_prep<<<BB, 256, 0, stream>>>(comp, sg, lat, sg_emb,
      lat_W1, lat_b1, lat_bn1_g, lat_bn1_b, lat_bn1_m, lat_bn1_v,
      lat_W2, lat_b2, lat_bn2_g, lat_bn2_b, lat_bn2_m, lat_bn2_v,
      sgx, latx, z, natoms);
  k_scan<<<1, 256, 0, stream>>>(natoms, off);
  k_physpe<<<NEL, 256, 0, stream>>>(period_idx, group_idx, z_emb, period_t, group_t,
      props, W_props, b_props, W_phys, b_phys, physpe);
  k_nodep<<<BB, 256, 0, stream>>>(z, off, natoms, physpe, latx, sgx, x0);

  k_wprep<<<dim3(PIN / 32, (3 * C1) / 32), 256, 0, stream>>>(gat1_W, wt1, PIN, 3 * C1);
  k_wprep<<<dim3(C1 / 32, (3 * C2) / 32), 256, 0, stream>>>(gat2_W, wt2, C1, 3 * C2);

  // ---- GAT layer 1 ----
  k_fold<<<C1, 64, 0, stream>>>(gat1_W, gat1_as, gat1_ad, 3 * C1, C1, wsv, wdv);
  k_av2<<<BB * NMAX, 64, 0, stream>>>(x0, wsv, wdv, off, natoms, asrc, adst, PIN);
  k_stats2<<<BB, 256, 0, stream>>>(asrc, adst, off, natoms, rowm, rows);
  k_fused_mfma<<<(C1 / 32) * BB, 256, 0, stream>>>(x0, wt1, asrc, adst, rowm, rows,
      off, natoms, gat1_b, x1, PIN, C1, C1 / 32);

  // ---- GAT layer 2 ----
  k_fold<<<C1, 64, 0, stream>>>(gat2_W, gat2_as, gat2_ad, 3 * C2, C2, wsv, wdv);
  k_av2<<<BB * NMAX, 64, 0, stream>>>(x1, wsv, wdv, off, natoms, asrc, adst, C1);
  k_stats2<<<BB, 256, 0, stream>>>(asrc, adst, off, natoms, rowm, rows);
  k_pad<<<1, 256, 0, stream>>>(gat1_b, gat2_W, gat2_b, pad2);
  k_fused_mfma<<<(C2 / 32) * BB, 256, 0, stream>>>(x1, wt2, asrc, adst, rowm, rows,
      off, natoms, gat2_b, x2, C1, C2, C2 / 32);

  // ---- readout + head ----
  k_feat2<<<BB, 256, 0, stream>>>(x2, pad2, off, natoms, sgx, latx, feat);
  k_head<<<BB, 256, 0, stream>>>(feat,
      pW1, pb1, pbn1_g, pbn1_b, pbn1_m, pbn1_v,
      pW2, pb2, pbn2_g, pbn2_b, pbn2_m, pbn2_v,
      pW3, pb3, (float*)d_out);
}

// Round 4
// 1265.098 us; speedup vs baseline: 5.8852x; 1.9910x over previous
//
#include <hip/hip_runtime.h>
#include <math.h>

#define BB 256
#define NEL 90
#define NMAX 270
#define C1 448
#define C2 256
#define PIN 448
#define LATH 128
#define SGE 64
#define P1 512
#define EPSB 1e-5f

typedef short shortx8 __attribute__((ext_vector_type(8)));
typedef float floatx4 __attribute__((ext_vector_type(4)));

__device__ __forceinline__ float bf2f(unsigned short u) {
  return __uint_as_float(((unsigned)u) << 16);
}
__device__ __forceinline__ unsigned short f2bf(float f) {
  unsigned x = __float_as_uint(f);
  unsigned r = (x + 0x7fffu + ((x >> 16) & 1u)) >> 16;
  return (unsigned short)r;
}

// ---------------- prep: cumsum -> z, n_atoms, sg_x, lat MLP ----------------
__global__ __launch_bounds__(256) void k_prep(
    const int* __restrict__ comp, const int* __restrict__ sg, const float* __restrict__ lat,
    const float* __restrict__ sg_emb,
    const float* __restrict__ W1, const float* __restrict__ b1,
    const float* __restrict__ g1, const float* __restrict__ be1,
    const float* __restrict__ m1, const float* __restrict__ v1,
    const float* __restrict__ W2, const float* __restrict__ b2,
    const float* __restrict__ g2, const float* __restrict__ be2,
    const float* __restrict__ m2, const float* __restrict__ v2,
    float* __restrict__ sgx, float* __restrict__ latx,
    int* __restrict__ z, int* __restrict__ natoms) {
  int b = blockIdx.x;
  int tid = threadIdx.x;
  __shared__ int cum[NEL];
  __shared__ float hbuf[LATH];
  __shared__ float latl[6];
  if (tid == 0) {
    int s = 0;
    for (int e = 0; e < NEL; ++e) { s += comp[b * NEL + e]; cum[e] = s; }
    natoms[b] = s;
  }
  if (tid < 6) latl[tid] = lat[b * 6 + tid];
  __syncthreads();
  int n = cum[NEL - 1];
  for (int t = tid; t < NMAX; t += blockDim.x) {
    int zz = -1;
    if (t < n) {
      for (int e = 0; e < NEL; ++e) { if (cum[e] > t) { zz = e; break; } }
    }
    z[b * NMAX + t] = zz;
  }
  if (tid < SGE) {
    int si = sg[b];
    sgx[b * SGE + tid] = sg_emb[si * SGE + tid];
  }
  if (tid < LATH) {
    float acc = b1[tid];
    for (int k = 0; k < 6; ++k) acc += latl[k] * W1[k * LATH + tid];
    acc = (acc - m1[tid]) * g1[tid] * rsqrtf(v1[tid] + EPSB) + be1[tid];
    hbuf[tid] = acc;
  }
  __syncthreads();
  if (tid < LATH) {
    float acc = b2[tid];
    for (int k = 0; k < LATH; ++k) acc += hbuf[k] * W2[k * LATH + tid];
    acc = (acc - m2[tid]) * g2[tid] * rsqrtf(v2[tid] + EPSB) + be2[tid];
    latx[b * LATH + tid] = acc;
  }
}

// ---------------- exclusive scan of natoms -> off ----------------
__global__ __launch_bounds__(256) void k_scan(const int* __restrict__ natoms,
                                              int* __restrict__ off) {
  __shared__ int sh[BB];
  int tid = threadIdx.x;
  int v0 = natoms[tid];
  sh[tid] = v0;
  for (int d = 1; d < BB; d <<= 1) {
    __syncthreads();
    int v = (tid >= d) ? sh[tid - d] : 0;
    __syncthreads();
    sh[tid] += v;
  }
  __syncthreads();
  off[tid] = sh[tid] - v0;
}

// ---------------- per-element-type phys rows: [90,256] ----------------
__global__ __launch_bounds__(256) void k_physpe(
    const int* __restrict__ period_idx, const int* __restrict__ group_idx,
    const float* __restrict__ z_emb, const float* __restrict__ period_t,
    const float* __restrict__ group_t, const float* __restrict__ props,
    const float* __restrict__ Wp, const float* __restrict__ bp,
    const float* __restrict__ Wphys, const float* __restrict__ bphys,
    float* __restrict__ physpe) {
  int e = blockIdx.x;
  int tid = threadIdx.x;
  __shared__ float ph[128];
  if (tid < 32) ph[tid] = z_emb[e * 32 + tid];
  else if (tid < 64) ph[tid] = period_t[period_idx[e] * 32 + tid - 32];
  else if (tid < 96) ph[tid] = group_t[group_idx[e] * 32 + tid - 64];
  else if (tid < 128) {
    int j = tid - 96;
    float acc = bp[j];
    for (int k = 0; k < 20; ++k) acc += props[e * 20 + k] * Wp[k * 32 + j];
    ph[tid] = acc;
  }
  __syncthreads();
  float acc = bphys[tid];
  for (int k = 0; k < 128; ++k) acc += ph[k] * Wphys[k * 256 + tid];
  physpe[e * 256 + tid] = acc;
}

// ---------------- packed node features x0 [total,448] bf16 ----------------
__global__ __launch_bounds__(256) void k_nodep(
    const int* __restrict__ z, const int* __restrict__ off, const int* __restrict__ natoms,
    const float* __restrict__ physpe, const float* __restrict__ latx,
    const float* __restrict__ sgx, unsigned short* __restrict__ x0) {
  int b = blockIdx.x;
  int n = natoms[b], ob = off[b];
  int tid = threadIdx.x;
  for (int e = tid; e < n * PIN; e += 256) {
    int t = e / PIN, c = e % PIN;
    int zt = z[b * NMAX + t];
    float v = (c < 256) ? physpe[zt * 256 + c]
            : (c < 384) ? latx[b * LATH + (c - 256)]
                        : sgx[b * SGE + (c - 384)];
    x0[(size_t)(ob + t) * PIN + c] = f2bf(v);
  }
}

// ---------------- W [K][3C] fp32 -> Wt [3C][K] bf16 (tile transpose) -------
__global__ __launch_bounds__(256) void k_wprep(
    const float* __restrict__ W, unsigned short* __restrict__ Wt, int K, int NC3) {
  int k0 = blockIdx.x << 5;
  int c0 = blockIdx.y << 5;
  __shared__ float ts[32][33];
  int e = threadIdx.x << 2;
  int kk = e >> 5, cc = e & 31;
  float4 v = *(const float4*)(W + (size_t)(k0 + kk) * NC3 + c0 + cc);
  ts[kk][cc] = v.x; ts[kk][cc + 1] = v.y; ts[kk][cc + 2] = v.z; ts[kk][cc + 3] = v.w;
  __syncthreads();
  int c2 = threadIdx.x & 31, kg = threadIdx.x >> 5;
  ushort4 u;
  u.x = f2bf(ts[kg * 4 + 0][c2]); u.y = f2bf(ts[kg * 4 + 1][c2]);
  u.z = f2bf(ts[kg * 4 + 2][c2]); u.w = f2bf(ts[kg * 4 + 3][c2]);
  *(ushort4*)(Wt + (size_t)(c0 + c2) * K + k0 + (kg << 2)) = u;
}

// ---------------- fold a_s/a_d through W: wsv/wdv [K][3] ----------------
__global__ __launch_bounds__(64) void k_fold(
    const float* __restrict__ W, const float* __restrict__ a_s, const float* __restrict__ a_d,
    int NC3, int C, float* __restrict__ wsv, float* __restrict__ wdv) {
  int k = blockIdx.x;
  int tid = threadIdx.x;
  for (int h = 0; h < 3; ++h) {
    float ss = 0.f, sd = 0.f;
    for (int c = tid; c < C; c += 64) {
      float wv = W[(size_t)k * NC3 + h * C + c];
      ss += wv * a_s[h * C + c];
      sd += wv * a_d[h * C + c];
    }
    for (int o = 32; o > 0; o >>= 1) { ss += __shfl_down(ss, o); sd += __shfl_down(sd, o); }
    if (tid == 0) { wsv[k * 3 + h] = ss; wdv[k * 3 + h] = sd; }
  }
}

// ---------------- asrc/adst for packed rows ----------------
__global__ __launch_bounds__(64) void k_av2(
    const unsigned short* __restrict__ x, const float* __restrict__ wsv,
    const float* __restrict__ wdv, const int* __restrict__ off,
    const int* __restrict__ natoms, float* __restrict__ asrc,
    float* __restrict__ adst, int K) {
  int row = blockIdx.x;
  int total = off[BB - 1] + natoms[BB - 1];
  if (row >= total) return;
  int tid = threadIdx.x;
  float s0 = 0.f, s1 = 0.f, s2 = 0.f, d0 = 0.f, d1 = 0.f, d2 = 0.f;
  for (int k = tid; k < K; k += 64) {
    float xv = bf2f(x[(size_t)row * K + k]);
    s0 += xv * wsv[k * 3 + 0]; s1 += xv * wsv[k * 3 + 1]; s2 += xv * wsv[k * 3 + 2];
    d0 += xv * wdv[k * 3 + 0]; d1 += xv * wdv[k * 3 + 1]; d2 += xv * wdv[k * 3 + 2];
  }
  for (int o = 32; o > 0; o >>= 1) {
    s0 += __shfl_down(s0, o); s1 += __shfl_down(s1, o); s2 += __shfl_down(s2, o);
    d0 += __shfl_down(d0, o); d1 += __shfl_down(d1, o); d2 += __shfl_down(d2, o);
  }
  if (tid == 0) {
    asrc[row * 3 + 0] = s0; asrc[row * 3 + 1] = s1; asrc[row * 3 + 2] = s2;
    adst[row * 3 + 0] = d0; adst[row * 3 + 1] = d1; adst[row * 3 + 2] = d2;
  }
}

// ---------------- per-row softmax stats (packed, j<n) ----------------
__global__ __launch_bounds__(256) void k_stats2(
    const float* __restrict__ asrc, const float* __restrict__ adst,
    const int* __restrict__ off, const int* __restrict__ natoms,
    float* __restrict__ rowm, float* __restrict__ rowsum) {
  int b = blockIdx.x;
  int n = natoms[b], ob = off[b];
  __shared__ float as_l[NMAX * 3];
  int tid = threadIdx.x;
  for (int e = tid; e < n * 3; e += 256) as_l[e] = asrc[ob * 3 + e];
  __syncthreads();
  for (int i = tid; i < n; i += 256) {
    for (int h = 0; h < 3; ++h) {
      float adv = adst[(ob + i) * 3 + h];
      float m = -1e30f;
      for (int j = 0; j < n; ++j) {
        float sc = as_l[j * 3 + h] + adv;
        sc = sc >= 0.f ? sc : 0.2f * sc;
        m = fmaxf(m, sc);
      }
      float s = 0.f;
      for (int j = 0; j < n; ++j) {
        float sc = as_l[j * 3 + h] + adv;
        sc = sc >= 0.f ? sc : 0.2f * sc;
        s += __expf(sc - m);
      }
      rowm[(ob + i) * 3 + h] = m;
      rowsum[(ob + i) * 3 + h] = s;
    }
  }
}

// ---------------- fused MFMA GAT layer ----------------
// grid: 1D NC*256 blocks, swizzled so a graph's col-blocks share bid%8 (XCD).
// Phase 1: t[j][c-tile 32] = x @ W_h (MFMA, A from LDS xs, B from LDS W^T tile)
// Phase 2: acc += alpha_h @ t (alpha built in-register in A-frag layout)
// NOTE: all per-thread tile arrays use COMPILE-TIME indices (MTW fixed, guarded
// by wave-uniform mt<mtn) so accumulators live in registers, never scratch.
#define XSS 40   // xs row stride (bf16): 80 B -> conflict-free b128 A-frags
#define TTS 296  // t^T row stride (bf16): 592 B
#define MTW 5    // max 16-row M tiles per wave: ceil(ceil(270/16)/4)=5

__global__ __launch_bounds__(256, 3) void k_fused_mfma(
    const unsigned short* __restrict__ xin, const unsigned short* __restrict__ Wt,
    const float* __restrict__ asrc, const float* __restrict__ adst,
    const float* __restrict__ rowm, const float* __restrict__ rowsum,
    const int* __restrict__ off, const int* __restrict__ natoms,
    const float* __restrict__ bias, unsigned short* __restrict__ xout,
    int K, int C, int NC) {
  int bid = blockIdx.x;
  int xg = bid & 7;
  int g = bid >> 3;
  int cblk = g % NC;
  int b = xg + ((g / NC) << 3);
  int c0 = cblk << 5;
  int n = natoms[b];
  int ob = off[b];
  int tid = threadIdx.x;
  int wv = tid >> 6;
  int lane = tid & 63;
  int m16 = lane & 15;
  int q = lane >> 4;

  int mtn = (n + 15) >> 4;   // 16-row M tiles
  int jmax = mtn << 4;
  int ktn = (n + 31) >> 5;   // phase-2 K steps
  int kext = ktn << 5;

  __shared__ unsigned short xs[272 * XSS];   // 21.75 KB
  __shared__ unsigned short tt[32 * TTS];    // 18.5 KB (overlaid by wt_s in phase 1)
  __shared__ float sm_as[288], sm_ad[288], sm_m[288], sm_rs[288];  // 4.5 KB
  unsigned short* wt_s = tt;

  floatx4 acc[MTW][2];
  #pragma unroll
  for (int i = 0; i < MTW; ++i) { acc[i][0] = (floatx4)0.f; acc[i][1] = (floatx4)0.f; }

  for (int h = 0; h < 3; ++h) {
    __syncthreads();  // prev head's phase-2 reads done
    for (int i2 = tid; i2 < kext; i2 += 256) {
      bool v = i2 < n;
      sm_as[i2] = v ? asrc[(ob + i2) * 3 + h] : 0.f;
      sm_ad[i2] = v ? adst[(ob + i2) * 3 + h] : 0.f;
      sm_m[i2]  = v ? rowm[(ob + i2) * 3 + h] : 0.f;
      sm_rs[i2] = v ? 1.f / rowsum[(ob + i2) * 3 + h] : 0.f;
    }
    floatx4 tac[MTW][2];
    #pragma unroll
    for (int i = 0; i < MTW; ++i) { tac[i][0] = (floatx4)0.f; tac[i][1] = (floatx4)0.f; }

    for (int k0 = 0; k0 < K; k0 += 32) {
      __syncthreads();
      // stage x tile [jmax][32] bf16 (zero rows >= n)
      for (int e = tid * 8; e < (jmax << 5); e += 2048) {
        int j = e >> 5, kk = e & 31;
        uint4 v = make_uint4(0u, 0u, 0u, 0u);
        if (j < n) v = *(const uint4*)(xin + (size_t)(ob + j) * K + k0 + kk);
        *(uint4*)(xs + j * XSS + kk) = v;
      }
      // stage W^T tile [32 c][32 k]
      {
        int r = tid >> 3, kk = (tid & 7) << 2;
        ushort4 wv4 = *(const ushort4*)(Wt + (size_t)(h * C + c0 + r) * K + k0 + kk);
        *(ushort4*)(wt_s + r * XSS + kk) = wv4;
      }
      __syncthreads();
      shortx8 b0 = *(const shortx8*)(wt_s + m16 * XSS + (q << 3));
      shortx8 b1 = *(const shortx8*)(wt_s + (16 + m16) * XSS + (q << 3));
      #pragma unroll
      for (int t_i = 0; t_i < MTW; ++t_i) {
        int mt = wv + (t_i << 2);
        if (mt < mtn) {
          shortx8 a = *(const shortx8*)(xs + ((mt << 4) + m16) * XSS + (q << 3));
          tac[t_i][0] = __builtin_amdgcn_mfma_f32_16x16x32_bf16(a, b0, tac[t_i][0], 0, 0, 0);
          tac[t_i][1] = __builtin_amdgcn_mfma_f32_16x16x32_bf16(a, b1, tac[t_i][1], 0, 0, 0);
        }
      }
    }
    __syncthreads();  // all waves done with wt_s
    // write t^T (cols c -> rows of tt, contiguous in j)
    {
      #pragma unroll
      for (int t_i = 0; t_i < MTW; ++t_i) {
        int mt = wv + (t_i << 2);
        if (mt < mtn) {
          int jr = (mt << 4) + (q << 2);
          #pragma unroll
          for (int nt = 0; nt < 2; ++nt) {
            floatx4 d = tac[t_i][nt];
            ushort4 u;
            u.x = f2bf(d.x); u.y = f2bf(d.y); u.z = f2bf(d.z); u.w = f2bf(d.w);
            *(ushort4*)(tt + ((nt << 4) + m16) * TTS + jr) = u;
          }
        }
      }
      int span = kext - jmax;
      for (int e = tid; e < (span << 5); e += 256) {
        int c = e / span, j = jmax + (e % span);
        tt[c * TTS + j] = 0;
      }
    }
    __syncthreads();  // tt ready
    // phase 2: acc += alpha_h @ t
    {
      float adr[MTW], mr[MTW], rsr[MTW];
      #pragma unroll
      for (int t_i = 0; t_i < MTW; ++t_i) {
        int mt = wv + (t_i << 2);
        int i = mt < mtn ? (mt << 4) + m16 : 0;
        adr[t_i] = sm_ad[i]; mr[t_i] = sm_m[i]; rsr[t_i] = sm_rs[i];
      }
      for (int k0p = 0; k0p < kext; k0p += 32) {
        shortx8 tb0 = *(const shortx8*)(tt + m16 * TTS + k0p + (q << 3));
        shortx8 tb1 = *(const shortx8*)(tt + (16 + m16) * TTS + k0p + (q << 3));
        float asj[8];
        #pragma unroll
        for (int j8 = 0; j8 < 8; ++j8) asj[j8] = sm_as[k0p + (q << 3) + j8];
        #pragma unroll
        for (int t_i = 0; t_i < MTW; ++t_i) {
          int mt = wv + (t_i << 2);
          if (mt < mtn) {
            shortx8 af;
            #pragma unroll
            for (int j8 = 0; j8 < 8; ++j8) {
              int j = k0p + (q << 3) + j8;
              float sc = asj[j8] + adr[t_i];
              sc = fmaxf(sc, 0.2f * sc);
              float al = __expf(sc - mr[t_i]) * rsr[t_i];
              af[j8] = (short)f2bf(j < n ? al : 0.f);
            }
            acc[t_i][0] = __builtin_amdgcn_mfma_f32_16x16x32_bf16(af, tb0, acc[t_i][0], 0, 0, 0);
            acc[t_i][1] = __builtin_amdgcn_mfma_f32_16x16x32_bf16(af, tb1, acc[t_i][1], 0, 0, 0);
          }
        }
      }
    }
  }
  // epilogue: mean over heads + bias, write bf16
  float bq0 = bias[c0 + m16];
  float bq1 = bias[c0 + 16 + m16];
  const float inv3 = 1.f / 3.f;
  #pragma unroll
  for (int t_i = 0; t_i < MTW; ++t_i) {
    int mt = wv + (t_i << 2);
    if (mt < mtn) {
      #pragma unroll
      for (int nt = 0; nt < 2; ++nt) {
        floatx4 d = acc[t_i][nt];
        float bq = nt ? bq1 : bq0;
        int cidx = c0 + (nt << 4) + m16;
        #pragma unroll
        for (int r = 0; r < 4; ++r) {
          int i = (mt << 4) + (q << 2) + r;
          if (i < n) xout[(size_t)(ob + i) * C + cidx] = f2bf(d[r] * inv3 + bq);
        }
      }
    }
  }
}

// ---------------- pad-row value after layer 2 ----------------
__global__ __launch_bounds__(256) void k_pad(
    const float* __restrict__ b1, const float* __restrict__ W2,
    const float* __restrict__ b2g, float* __restrict__ pad2) {
  int c = threadIdx.x;  // 256
  float s = 0.f;
  for (int h = 0; h < 3; ++h)
    for (int k = 0; k < C1; ++k)
      s += b1[k] * W2[(size_t)k * (3 * C2) + h * C2 + c];
  pad2[c] = s * (1.f / 3.f) + b2g[c];
}

// ---------------- readout: comp_x + concat ----------------
__global__ __launch_bounds__(256) void k_feat2(
    const unsigned short* __restrict__ x2, const float* __restrict__ pad2,
    const int* __restrict__ off, const int* __restrict__ natoms,
    const float* __restrict__ sgx, const float* __restrict__ latx,
    float* __restrict__ feat) {
  int b = blockIdx.x, tid = threadIdx.x;
  int n = natoms[b], ob = off[b];
  float s = (float)(NMAX - n) * pad2[tid];
  for (int i = 0; i < n; ++i) s += bf2f(x2[(size_t)(ob + i) * C2 + tid]);
  feat[b * PIN + tid] = s;
  if (tid < SGE) feat[b * PIN + 256 + tid] = sgx[b * SGE + tid];
  if (tid < LATH) feat[b * PIN + 320 + tid] = latx[b * LATH + tid];
}

// ---------------- head MLP ----------------
__global__ __launch_bounds__(256) void k_head(
    const float* __restrict__ feat,
    const float* __restrict__ W1, const float* __restrict__ b1,
    const float* __restrict__ g1, const float* __restrict__ be1,
    const float* __restrict__ m1, const float* __restrict__ v1,
    const float* __restrict__ W2, const float* __restrict__ b2,
    const float* __restrict__ g2, const float* __restrict__ be2,
    const float* __restrict__ m2, const float* __restrict__ v2,
    const float* __restrict__ W3, const float* __restrict__ b3,
    float* __restrict__ out) {
  int b = blockIdx.x, tid = threadIdx.x;
  __shared__ float f[PIN];
  __shared__ float h1[P1];
  __shared__ float h2[P1];
  __shared__ float red[256];
  for (int i = tid; i < PIN; i += 256) f[i] = feat[b * PIN + i];
  __syncthreads();
  for (int o = tid; o < P1; o += 256) {
    float acc = b1[o];
    for (int k = 0; k < PIN; ++k) acc += f[k] * W1[k * P1 + o];
    acc = (acc - m1[o]) * g1[o] * rsqrtf(v1[o] + EPSB) + be1[o];
    h1[o] = acc >= 0.f ? acc : 0.2f * acc;
  }
  __syncthreads();
  for (int o = tid; o < P1; o += 256) {
    float acc = b2[o];
    for (int k = 0; k < P1; ++k) acc += h1[k] * W2[k * P1 + o];
    acc = (acc - m2[o]) * g2[o] * rsqrtf(v2[o] + EPSB) + be2[o];
    h2[o] = acc >= 0.f ? acc : 0.2f * acc;
  }
  __syncthreads();
  float p = 0.f;
  for (int k = tid; k < P1; k += 256) p += h2[k] * W3[k];
  red[tid] = p;
  __syncthreads();
  for (int s = 128; s > 0; s >>= 1) {
    if (tid < s) red[tid] += red[tid + s];
    __syncthreads();
  }
  if (tid == 0) out[b] = red[0] + b3[0];
}

extern "C" void kernel_launch(void* const* d_in, const int* in_sizes, int n_in,
                              void* d_out, int out_size, void* d_ws, size_t ws_size,
                              hipStream_t stream) {
  const int*   comp       = (const int*)d_in[0];
  const int*   sg         = (const int*)d_in[1];
  const float* lat        = (const float*)d_in[2];
  const int*   period_idx = (const int*)d_in[3];
  const int*   group_idx  = (const int*)d_in[4];
  const float* sg_emb     = (const float*)d_in[5];
  const float* lat_W1     = (const float*)d_in[6];
  const float* lat_b1     = (const float*)d_in[7];
  const float* lat_bn1_g  = (const float*)d_in[8];
  const float* lat_bn1_b  = (const float*)d_in[9];
  const float* lat_bn1_m  = (const float*)d_in[10];
  const float* lat_bn1_v  = (const float*)d_in[11];
  const float* lat_W2     = (const float*)d_in[12];
  const float* lat_b2     = (const float*)d_in[13];
  const float* lat_bn2_g  = (const float*)d_in[14];
  const float* lat_bn2_b  = (const float*)d_in[15];
  const float* lat_bn2_m  = (const float*)d_in[16];
  const float* lat_bn2_v  = (const float*)d_in[17];
  const float* z_emb      = (const float*)d_in[18];
  const float* period_t   = (const float*)d_in[19];
  const float* group_t    = (const float*)d_in[20];
  const float* props      = (const float*)d_in[21];
  const float* W_props    = (const float*)d_in[22];
  const float* b_props    = (const float*)d_in[23];
  const float* W_phys     = (const float*)d_in[24];
  const float* b_phys     = (const float*)d_in[25];
  const float* gat1_W     = (const float*)d_in[26];
  const float* gat1_as    = (const float*)d_in[27];
  const float* gat1_ad    = (const float*)d_in[28];
  const float* gat1_b     = (const float*)d_in[29];
  const float* gat2_W     = (const float*)d_in[30];
  const float* gat2_as    = (const float*)d_in[31];
  const float* gat2_ad    = (const float*)d_in[32];
  const float* gat2_b     = (const float*)d_in[33];
  const float* pW1        = (const float*)d_in[34];
  const float* pb1        = (const float*)d_in[35];
  const float* pbn1_g     = (const float*)d_in[36];
  const float* pbn1_b     = (const float*)d_in[37];
  const float* pbn1_m     = (const float*)d_in[38];
  const float* pbn1_v     = (const float*)d_in[39];
  const float* pW2        = (const float*)d_in[40];
  const float* pb2        = (const float*)d_in[41];
  const float* pbn2_g     = (const float*)d_in[42];
  const float* pbn2_b     = (const float*)d_in[43];
  const float* pbn2_m     = (const float*)d_in[44];
  const float* pbn2_v     = (const float*)d_in[45];
  const float* pW3        = (const float*)d_in[46];
  const float* pb3        = (const float*)d_in[47];

  float* ws = (float*)d_ws;
  const size_t o_sgx  = 0;
  const size_t o_latx = o_sgx  + (size_t)BB * SGE;
  const size_t o_nat  = o_latx + (size_t)BB * LATH;
  const size_t o_off  = o_nat  + BB;
  const size_t o_z    = o_off  + BB;
  const size_t o_phys = o_z    + (size_t)BB * NMAX;
  const size_t o_wsv  = o_phys + (size_t)NEL * 256;
  const size_t o_wdv  = o_wsv  + (size_t)C1 * 3;
  const size_t o_asrc = o_wdv  + (size_t)C1 * 3;
  const size_t o_adst = o_asrc + (size_t)BB * NMAX * 3;
  const size_t o_rm   = o_adst + (size_t)BB * NMAX * 3;
  const size_t o_rs   = o_rm   + (size_t)BB * NMAX * 3;
  const size_t o_pad2 = o_rs   + (size_t)BB * NMAX * 3;
  const size_t o_wt1  = o_pad2 + 256;
  const size_t o_wt2  = o_wt1  + (size_t)(3 * C1) * PIN / 2;  // bf16 region
  const size_t o_x0   = o_wt2  + (size_t)(3 * C2) * C1 / 2;   // bf16 region
  const size_t o_x1   = o_x0   + (size_t)BB * NMAX * PIN / 2;

  float* sgx    = ws + o_sgx;
  float* latx   = ws + o_latx;
  int*   natoms = (int*)(ws + o_nat);
  int*   off    = (int*)(ws + o_off);
  int*   z      = (int*)(ws + o_z);
  float* physpe = ws + o_phys;
  float* wsv    = ws + o_wsv;
  float* wdv    = ws + o_wdv;
  float* asrc   = ws + o_asrc;
  float* adst   = ws + o_adst;
  float* rowm   = ws + o_rm;
  float* rows   = ws + o_rs;
  float* pad2   = ws + o_pad2;
  unsigned short* wt1 = (unsigned short*)(ws + o_wt1);  // [1344,448] bf16
  unsigned short* wt2 = (unsigned short*)(ws + o_wt2);  // [768,448] bf16
  unsigned short* x0  = (unsigned short*)(ws + o_x0);   // [total,448] bf16
  unsigned short* x1  = (unsigned short*)(ws + o_x1);   // [total,448] bf16
  unsigned short* x2  = x0;                              // [total,256] reuse
  float* feat   = ws + o_x1;                             // reuse after layer 2

  k_prep<<<BB, 256, 0, stream>>>(comp, sg, lat, sg_emb,
      lat_W1, lat_b1, lat_bn1_g, lat_bn1_b, lat_bn1_m, lat_bn1_v,
      lat_W2, lat_b2, lat_bn2_g, lat_bn2_b, lat_bn2_m, lat_bn2_v,
      sgx, latx, z, natoms);
  k_scan<<<1, 256, 0, stream>>>(natoms, off);
  k_physpe<<<NEL, 256, 0, stream>>>(period_idx, group_idx, z_emb, period_t, group_t,
      props, W_props, b_props, W_phys, b_phys, physpe);
  k_nodep<<<BB, 256, 0, stream>>>(z, off, natoms, physpe, latx, sgx, x0);

  k_wprep<<<dim3(PIN / 32, (3 * C1) / 32), 256, 0, stream>>>(gat1_W, wt1, PIN, 3 * C1);
  k_wprep<<<dim3(C1 / 32, (3 * C2) / 32), 256, 0, stream>>>(gat2_W, wt2, C1, 3 * C2);

  // ---- GAT layer 1 ----
  k_fold<<<C1, 64, 0, stream>>>(gat1_W, gat1_as, gat1_ad, 3 * C1, C1, wsv, wdv);
  k_av2<<<BB * NMAX, 64, 0, stream>>>(x0, wsv, wdv, off, natoms, asrc, adst, PIN);
  k_stats2<<<BB, 256, 0, stream>>>(asrc, adst, off, natoms, rowm, rows);
  k_fused_mfma<<<(C1 / 32) * BB, 256, 0, stream>>>(x0, wt1, asrc, adst, rowm, rows,
      off, natoms, gat1_b, x1, PIN, C1, C1 / 32);

  // ---- GAT layer 2 ----
  k_fold<<<C1, 64, 0, stream>>>(gat2_W, gat2_as, gat2_ad, 3 * C2, C2, wsv, wdv);
  k_av2<<<BB * NMAX, 64, 0, stream>>>(x1, wsv, wdv, off, natoms, asrc, adst, C1);
  k_stats2<<<BB, 256, 0, stream>>>(asrc, adst, off, natoms, rowm, rows);
  k_pad<<<1, 256, 0, stream>>>(gat1_b, gat2_W, gat2_b, pad2);
  k_fused_mfma<<<(C2 / 32) * BB, 256, 0, stream>>>(x1, wt2, asrc, adst, rowm, rows,
      off, natoms, gat2_b, x2, C1, C2, C2 / 32);

  // ---- readout + head ----
  k_feat2<<<BB, 256, 0, stream>>>(x2, pad2, off, natoms, sgx, latx, feat);
  k_head<<<BB, 256, 0, stream>>>(feat,
      pW1, pb1, pbn1_g, pbn1_b, pbn1_m, pbn1_v,
      pW2, pb2, pbn2_g, pbn2_b, pbn2_m, pbn2_v,
      pW3, pb3, (float*)d_out);
}